// Round 1
// baseline (1511.952 us; speedup 1.0000x reference)
//
#include <hip/hip_runtime.h>
#include <math.h>

#define N_   32
#define C_   256
#define T_   128
#define V_   25
#define DK_  64
#define DV_  256
#define NH_  8
#define DKH_ 8
#define DVH_ 32
#define EPS_ 1e-5f
#define STRIDE 28   // padded row stride (floats): 112 B, 16B-aligned rows

// qkvbuf row map: 0..63 q(scaled) | 64..127 k | 128..191 g | 192..447 v | 448..511 pq(scaled) | 512..575 pk

__global__ void prep_kernel(const float* __restrict__ qkv_w,
                            float* __restrict__ Wt, float* __restrict__ pe) {
    int idx = blockIdx.x * blockDim.x + threadIdx.x;
    int stride = gridDim.x * blockDim.x;
    // Wt[c][o] = qkv_w[o][c]  (448x256 -> 256x448)
    for (int i = idx; i < 448 * 256; i += stride) {
        int o = i >> 8, c = i & 255;
        Wt[c * 448 + o] = qkv_w[i];
    }
    // spatial PE: channel c, joint v
    for (int i = idx; i < C_ * V_; i += stride) {
        int c = i / V_, v = i - c * V_;
        int j2 = c & ~1;  // 2*(c/2)
        float ang = (float)v * expf(-logf(10000.0f) * (float)j2 / (float)C_);
        pe[i] = (c & 1) ? cosf(ang) : sinf(ang);
    }
}

__global__ void dbn_stats_kernel(const float* __restrict__ x,
                                 const float* __restrict__ gamma,
                                 const float* __restrict__ beta,
                                 float* __restrict__ a_scale,
                                 float* __restrict__ a_shift) {
    int f = blockIdx.x;  // f = c*V + v
    int c = f / V_, v = f - c * V_;
    const float* xp = x + (size_t)c * (T_ * V_) + v;
    float s = 0.f, s2 = 0.f;
    for (int i = threadIdx.x; i < N_ * T_; i += 256) {
        int n = i >> 7, t = i & 127;
        float val = xp[(size_t)n * (C_ * T_ * V_) + t * V_];
        s += val; s2 += val * val;
    }
    __shared__ float sh[8];
    #pragma unroll
    for (int off = 32; off; off >>= 1) {
        s  += __shfl_down(s, off, 64);
        s2 += __shfl_down(s2, off, 64);
    }
    int wid = threadIdx.x >> 6, lane = threadIdx.x & 63;
    if (lane == 0) { sh[wid] = s; sh[4 + wid] = s2; }
    __syncthreads();
    if (threadIdx.x == 0) {
        s = sh[0] + sh[1] + sh[2] + sh[3];
        s2 = sh[4] + sh[5] + sh[6] + sh[7];
        float inv = 1.0f / (float)(N_ * T_);
        float mean = s * inv;
        float var = s2 * inv - mean * mean;
        float sc = rsqrtf(var + EPS_) * gamma[f];
        a_scale[f] = sc;
        a_shift[f] = beta[f] - mean * sc;
    }
}

__global__ __launch_bounds__(576, 1) void fused_kernel(
        const float* __restrict__ x, const float* __restrict__ Wt,
        const float* __restrict__ qkv_b, const float* __restrict__ pe,
        const float* __restrict__ a_scale, const float* __restrict__ a_shift,
        const float* __restrict__ attn_w, const float* __restrict__ attn_b,
        float* __restrict__ out) {
    __shared__ float xbuf[256][STRIDE];   // raw x tile, lives to the end (skip)
    __shared__ float buf1[256][STRIDE];   // pos; later attn (256x25)
    __shared__ float buf2[256][STRIDE];   // xn;  later weights (8*25*25 = 5000 floats)
    __shared__ float qkvbuf[576][STRIDE];
    __shared__ float qmu[64];

    int blk = blockIdx.x;           // n*T + t
    int n = blk >> 7, t = blk & 127;
    int tid = threadIdx.x;
    const float* xp = x + (size_t)n * (C_ * T_ * V_) + t * V_;

    // ---- stage x, pos = x+pe, xn = a_scale*x + a_shift ----
    for (int i = tid; i < C_ * V_; i += 576) {
        int c = i / V_, v = i - c * V_;
        float xv = xp[c * (T_ * V_) + v];
        xbuf[c][v] = xv;
        buf1[c][v] = xv + pe[i];
        buf2[c][v] = fmaf(xv, a_scale[i], a_shift[i]);
    }
    __syncthreads();

    // ---- GEMM1: one output row per thread (576 rows) ----
    {
        int r = tid;
        int wrow = (r < 448) ? r : (r - 448);
        const float (*B)[STRIDE] = (r < 448) ? (const float (*)[STRIDE])buf2
                                             : (const float (*)[STRIDE])buf1;
        float acc[25];
        #pragma unroll
        for (int v = 0; v < 25; ++v) acc[v] = 0.f;
        const float* wp = Wt + wrow;
        #pragma unroll 4
        for (int c = 0; c < 256; ++c) {
            float w = wp[c * 448];
            #pragma unroll
            for (int v = 0; v < 25; ++v) acc[v] = fmaf(w, B[c][v], acc[v]);
        }
        float bias = qkv_b[wrow];
        float scale = ((r < 64) || (r >= 448 && r < 512)) ? 0.35355339059327373f : 1.0f;
        #pragma unroll
        for (int v = 0; v < 25; ++v) qkvbuf[r][v] = (acc[v] + bias) * scale;
    }
    __syncthreads();

    // ---- per-(h,d) q mean over joints ----
    if (tid < 64) {
        float s = 0.f;
        #pragma unroll
        for (int v = 0; v < 25; ++v) s += qkvbuf[tid][v];
        qmu[tid] = s * (1.0f / 25.0f);
    }
    __syncthreads();

    // ---- attention weights: tanh(pair+lp) + tanh(unary+lp) ----
    float* wbuf = &buf2[0][0];  // 5000 floats
    for (int i = tid; i < NH_ * V_ * V_; i += 576) {
        int h = i / (V_ * V_);
        int rem = i - h * (V_ * V_);
        int v = rem / V_, w = rem - v * V_;
        int qb = h * 8;
        float pair = 0.f, lpv = 0.f, un = 0.f;
        #pragma unroll
        for (int d = 0; d < 8; ++d) {
            float m = qmu[qb + d];
            pair += (qkvbuf[qb + d][v] - m) * qkvbuf[64 + qb + d][w];
            lpv  += qkvbuf[448 + qb + d][v] * qkvbuf[512 + qb + d][w];
            un   += m * qkvbuf[128 + qb + d][w];
        }
        wbuf[i] = tanhf(pair + lpv) + tanhf(un + lpv);
    }
    __syncthreads();

    // ---- attn = weights x V  ->  abuf[e_global][v] ----
    float (*abuf)[STRIDE] = (float (*)[STRIDE])buf1;
    for (int i = tid; i < DV_ * V_; i += 576) {
        int eg = i / V_, v = i - eg * V_;
        int h = eg >> 5;
        const float* wrow_ = wbuf + h * (V_ * V_) + v * V_;
        const float* vrow = &qkvbuf[192 + eg][0];
        float s = 0.f;
        #pragma unroll
        for (int w = 0; w < 25; ++w) s = fmaf(wrow_[w], vrow[w], s);
        abuf[eg][v] = s;
    }
    __syncthreads();

    // ---- GEMM2: out[o][v] = attn_w[o,:] . abuf[:, v] + b[o] + x (skip) ----
    float* outp = out + (size_t)n * (C_ * T_ * V_) + t * V_;
    for (int item = tid; item < 256 * 5; item += 576) {
        int o = item / 5, vb = (item - o * 5) * 5;
        const float* aw = attn_w + o * 256;
        float acc[5] = {0.f, 0.f, 0.f, 0.f, 0.f};
        #pragma unroll 4
        for (int e = 0; e < 256; ++e) {
            float w = aw[e];
            #pragma unroll
            for (int j = 0; j < 5; ++j) acc[j] = fmaf(w, abuf[e][vb + j], acc[j]);
        }
        float bias = attn_b[o];
        #pragma unroll
        for (int j = 0; j < 5; ++j)
            outp[o * (T_ * V_) + vb + j] = acc[j] + bias + xbuf[o][vb + j];
    }
}

__global__ void bn2_stats_kernel(const float* __restrict__ y,
                                 const float* __restrict__ gamma,
                                 const float* __restrict__ beta,
                                 float* __restrict__ scale,
                                 float* __restrict__ shift) {
    int c = blockIdx.x;
    const float* yp = y + (size_t)c * (T_ * V_);
    float s = 0.f, s2 = 0.f;
    for (int i = threadIdx.x; i < N_ * T_ * V_; i += 256) {
        int n = i / (T_ * V_), j = i - n * (T_ * V_);
        float val = yp[(size_t)n * (C_ * T_ * V_) + j];
        s += val; s2 += val * val;
    }
    __shared__ float sh[8];
    #pragma unroll
    for (int off = 32; off; off >>= 1) {
        s  += __shfl_down(s, off, 64);
        s2 += __shfl_down(s2, off, 64);
    }
    int wid = threadIdx.x >> 6, lane = threadIdx.x & 63;
    if (lane == 0) { sh[wid] = s; sh[4 + wid] = s2; }
    __syncthreads();
    if (threadIdx.x == 0) {
        s = sh[0] + sh[1] + sh[2] + sh[3];
        s2 = sh[4] + sh[5] + sh[6] + sh[7];
        float inv = 1.0f / (float)(N_ * T_ * V_);
        float mean = s * inv;
        float var = s2 * inv - mean * mean;
        float sc = rsqrtf(var + EPS_) * gamma[c];
        scale[c] = sc;
        shift[c] = beta[c] - mean * sc;
    }
}

__global__ void bn2_apply_kernel(float4* __restrict__ y,
                                 const float* __restrict__ scale,
                                 const float* __restrict__ shift) {
    const int total4 = N_ * C_ * T_ * V_ / 4;  // 6,553,600
    for (int i = blockIdx.x * blockDim.x + threadIdx.x; i < total4;
         i += gridDim.x * blockDim.x) {
        int c = (i / (T_ * V_ / 4)) & 255;  // 800 float4 per (n,c)
        float4 v = y[i];
        float sc = scale[c], sh = shift[c];
        v.x = fmaxf(fmaf(v.x, sc, sh), 0.f);
        v.y = fmaxf(fmaf(v.y, sc, sh), 0.f);
        v.z = fmaxf(fmaf(v.z, sc, sh), 0.f);
        v.w = fmaxf(fmaf(v.w, sc, sh), 0.f);
        y[i] = v;
    }
}

extern "C" void kernel_launch(void* const* d_in, const int* in_sizes, int n_in,
                              void* d_out, int out_size, void* d_ws, size_t ws_size,
                              hipStream_t stream) {
    const float* x      = (const float*)d_in[0];
    const float* qkv_w  = (const float*)d_in[1];
    const float* qkv_b  = (const float*)d_in[2];
    const float* attn_w = (const float*)d_in[3];
    const float* attn_b = (const float*)d_in[4];
    const float* dbn_g  = (const float*)d_in[5];
    const float* dbn_b  = (const float*)d_in[6];
    const float* bn_g   = (const float*)d_in[7];
    const float* bn_b   = (const float*)d_in[8];
    float* out = (float*)d_out;

    float* ws       = (float*)d_ws;
    float* Wt       = ws;                    // 448*256 = 114688
    float* pe       = Wt + 114688;           // 6400
    float* a_scale  = pe + 6400;             // 6400
    float* a_shift  = a_scale + 6400;        // 6400
    float* bn2_sc   = a_shift + 6400;        // 256
    float* bn2_sh   = bn2_sc + 256;          // 256

    prep_kernel<<<256, 256, 0, stream>>>(qkv_w, Wt, pe);
    dbn_stats_kernel<<<C_ * V_, 256, 0, stream>>>(x, dbn_g, dbn_b, a_scale, a_shift);
    fused_kernel<<<N_ * T_, 576, 0, stream>>>(x, Wt, qkv_b, pe, a_scale, a_shift,
                                              attn_w, attn_b, out);
    bn2_stats_kernel<<<C_, 256, 0, stream>>>(out, bn_g, bn_b, bn2_sc, bn2_sh);
    bn2_apply_kernel<<<4096, 256, 0, stream>>>((float4*)out, bn2_sc, bn2_sh);
}

// Round 2
// 629.693 us; speedup vs baseline: 2.4011x; 2.4011x over previous
//
#include <hip/hip_runtime.h>
#include <hip/hip_bf16.h>
#include <math.h>

#define N_   32
#define C_   256
#define T_   128
#define V_   25
#define CTV  (C_ * T_ * V_)   // 819200
#define TV   (T_ * V_)        // 3200
#define EPS_ 1e-5f
#define BSTR 264              // padded row (bf16 elems) for transposed B tiles

typedef __attribute__((ext_vector_type(8))) short bf16x8;
typedef __attribute__((ext_vector_type(4))) float f32x4;

__device__ inline ushort f2b(float f) {
    __hip_bfloat16 h = __float2bfloat16(f);
    return *reinterpret_cast<ushort*>(&h);
}
__device__ inline float b2f(ushort u) {
    __hip_bfloat16 h;
    *reinterpret_cast<ushort*>(&h) = u;
    return __bfloat162float(h);
}

// ---------------- prep: bf16 weights + PE table ----------------
__global__ void prep_kernel(const float* __restrict__ qkv_w,
                            const float* __restrict__ attn_w,
                            ushort* __restrict__ Wq,   // 448x256 bf16
                            ushort* __restrict__ Wa,   // 256x256 bf16
                            float* __restrict__ pe) {
    int idx = blockIdx.x * blockDim.x + threadIdx.x;
    int stride = gridDim.x * blockDim.x;
    for (int i = idx; i < 448 * 256; i += stride) Wq[i] = f2b(qkv_w[i]);
    for (int i = idx; i < 256 * 256; i += stride) Wa[i] = f2b(attn_w[i]);
    for (int i = idx; i < C_ * V_; i += stride) {
        int c = i / V_, v = i - c * V_;
        int j2 = c & ~1;
        float ang = (float)v * expf(-logf(10000.0f) * (float)j2 / (float)C_);
        pe[i] = (c & 1) ? cosf(ang) : sinf(ang);
    }
}

// ---------------- data_bn stats -> per (c,v) affine ----------------
__global__ void dbn_stats_kernel(const float* __restrict__ x,
                                 const float* __restrict__ gamma,
                                 const float* __restrict__ beta,
                                 float* __restrict__ a_scale,
                                 float* __restrict__ a_shift) {
    int f = blockIdx.x;  // f = c*V + v
    int c = f / V_, v = f - c * V_;
    const float* xp = x + (size_t)c * TV + v;
    float s = 0.f, s2 = 0.f;
    for (int i = threadIdx.x; i < N_ * T_; i += 256) {
        int n = i >> 7, t = i & 127;
        float val = xp[(size_t)n * CTV + t * V_];
        s += val; s2 += val * val;
    }
    __shared__ float sh[8];
    #pragma unroll
    for (int off = 32; off; off >>= 1) {
        s  += __shfl_down(s, off, 64);
        s2 += __shfl_down(s2, off, 64);
    }
    int wid = threadIdx.x >> 6, lane = threadIdx.x & 63;
    if (lane == 0) { sh[wid] = s; sh[4 + wid] = s2; }
    __syncthreads();
    if (threadIdx.x == 0) {
        s = sh[0] + sh[1] + sh[2] + sh[3];
        s2 = sh[4] + sh[5] + sh[6] + sh[7];
        float inv = 1.0f / (float)(N_ * T_);
        float mean = s * inv;
        float var = s2 * inv - mean * mean;
        float sc = rsqrtf(var + EPS_) * gamma[f];
        a_scale[f] = sc;
        a_shift[f] = beta[f] - mean * sc;
    }
}

// ---------------- fused per-token kernel (MFMA GEMMs) ----------------
// qkv row map: 0..63 q | 64..127 k | 128..191 g | 192..447 v | 448..511 pq | 512..575 pk
__global__ __launch_bounds__(512) void fused_kernel(
        const float* __restrict__ x,
        const ushort* __restrict__ Wq, const float* __restrict__ qkv_b,
        const float* __restrict__ pe,
        const float* __restrict__ a_scale, const float* __restrict__ a_shift,
        const ushort* __restrict__ Wa, const float* __restrict__ attn_b,
        float* __restrict__ out) {
    // LDS layout (bytes):
    //   [0,16896)      xnT  [32][BSTR] bf16   -> reused as aT (attn out ^T)
    //   [16896,33792)  posT [32][BSTR] bf16   -> reused (with wextra) as wbuf f32[5000]
    //   [33792,36896)  wextra (tail of wbuf)
    //   [36896,73760)  qkv  [576][32] bf16
    //   [73760,74016)  qmu  f32[64]
    __shared__ __align__(16) char smem[74016];
    ushort* xnT  = (ushort*)smem;
    ushort* posT = (ushort*)(smem + 16896);
    float*  wbuf = (float*)(smem + 16896);   // 5000 floats (spans posT+wextra)
    ushort* aT   = xnT;
    ushort* qkv  = (ushort*)(smem + 36896);
    float*  qmu  = (float*)(smem + 73760);

    int blk = blockIdx.x;
    int n = blk >> 7, t = blk & 127;
    int tid = threadIdx.x;
    int wave = tid >> 6, lane = tid & 63;
    int lr = lane & 15, lg = lane >> 4;   // row/col-in-tile, k-octet group
    const float* xp = x + (size_t)n * CTV + t * V_;

    // ---- stage: xnT[v][c], posT[v][c] (bf16, transposed) ----
    for (int i = tid; i < C_ * V_; i += 512) {
        int c = i / V_, v = i - c * V_;
        float xv = xp[c * TV + v];
        xnT[v * BSTR + c]  = f2b(fmaf(xv, a_scale[i], a_shift[i]));
        posT[v * BSTR + c] = f2b(xv + pe[i]);
    }
    for (int i = tid; i < 7 * 256; i += 512) {  // zero pad rows v=25..31
        int v = 25 + i / 256, c = i & 255;
        xnT[v * BSTR + c] = 0;
        posT[v * BSTR + c] = 0;
    }
    __syncthreads();

    // ---- GEMM1: qkv[576][25] = W(576x256) x B(256x25), MFMA ----
    for (int mt = wave; mt < 36; mt += 8) {
        const ushort* Bsrc = (mt < 28) ? xnT : posT;
        int r0 = mt * 16;
        int wr0 = (mt < 28) ? r0 : (r0 - 448);      // W/bias row base
        const ushort* Arow = Wq + (wr0 + lr) * 256;
        f32x4 acc0 = {0.f, 0.f, 0.f, 0.f}, acc1 = {0.f, 0.f, 0.f, 0.f};
        #pragma unroll
        for (int kk = 0; kk < 8; ++kk) {
            int k0 = kk * 32 + lg * 8;
            bf16x8 a  = *(const bf16x8*)(Arow + k0);
            bf16x8 b0 = *(const bf16x8*)(Bsrc + lr * BSTR + k0);
            bf16x8 b1 = *(const bf16x8*)(Bsrc + (16 + lr) * BSTR + k0);
            acc0 = __builtin_amdgcn_mfma_f32_16x16x32_bf16(a, b0, acc0, 0, 0, 0);
            acc1 = __builtin_amdgcn_mfma_f32_16x16x32_bf16(a, b1, acc1, 0, 0, 0);
        }
        float scale = (mt < 4 || (mt >= 28 && mt < 32)) ? 0.35355339059327373f : 1.0f;
        #pragma unroll
        for (int i2 = 0; i2 < 4; ++i2) {
            int row = r0 + lg * 4 + i2;
            float bias = qkv_b[wr0 + lg * 4 + i2];
            qkv[row * 32 + lr]      = f2b((acc0[i2] + bias) * scale);
            qkv[row * 32 + 16 + lr] = f2b((acc1[i2] + bias) * scale);
        }
    }
    __syncthreads();

    // ---- per-(h,d) q mean over joints ----
    if (tid < 64) {
        float s = 0.f;
        #pragma unroll
        for (int v = 0; v < 25; ++v) s += b2f(qkv[tid * 32 + v]);
        qmu[tid] = s * (1.0f / 25.0f);
    }
    __syncthreads();

    // ---- weights = tanh(pair+lp) + tanh(unary+lp) ----
    for (int i = tid; i < 8 * 625; i += 512) {
        int h = i / 625;
        int rem = i - h * 625;
        int v = rem / 25, w = rem - v * 25;
        int qb = h * 8;
        float pair = 0.f, lpv = 0.f, un = 0.f;
        #pragma unroll
        for (int d = 0; d < 8; ++d) {
            float m = qmu[qb + d];
            float qv = b2f(qkv[(qb + d) * 32 + v]);
            float kw = b2f(qkv[(64 + qb + d) * 32 + w]);
            float gw = b2f(qkv[(128 + qb + d) * 32 + w]);
            float pqv = b2f(qkv[(448 + qb + d) * 32 + v]);
            float pkw = b2f(qkv[(512 + qb + d) * 32 + w]);
            pair += (qv - m) * kw;
            lpv  += pqv * pkw;
            un   += m * gw;
        }
        wbuf[i] = tanhf(pair + lpv) + tanhf(un + lpv);
    }
    __syncthreads();

    // ---- attn = weights x V  -> aT[v][e] (bf16, transposed), zero-pad rows ----
    for (int i = tid; i < 256 * 25; i += 512) {
        int eg = i / 25, v = i - eg * 25;
        int h = eg >> 5;
        const float* wrow_ = wbuf + h * 625 + v * 25;
        const ushort* vrow = qkv + (192 + eg) * 32;
        float s = 0.f;
        #pragma unroll
        for (int w = 0; w < 25; ++w) s = fmaf(wrow_[w], b2f(vrow[w]), s);
        aT[v * BSTR + eg] = f2b(s);
    }
    for (int i = tid; i < 7 * 256; i += 512) {
        int v = 25 + i / 256, c = i & 255;
        aT[v * BSTR + c] = 0;
    }
    __syncthreads();

    // ---- GEMM2: out = attn_w(256x256) x aT^T(256x25) + bias + skip ----
    float* outp = out + (size_t)n * CTV + t * V_;
    for (int mt = wave; mt < 16; mt += 8) {
        int o0 = mt * 16;
        const ushort* Arow = Wa + (o0 + lr) * 256;
        f32x4 acc0 = {0.f, 0.f, 0.f, 0.f}, acc1 = {0.f, 0.f, 0.f, 0.f};
        #pragma unroll
        for (int kk = 0; kk < 8; ++kk) {
            int k0 = kk * 32 + lg * 8;
            bf16x8 a  = *(const bf16x8*)(Arow + k0);
            bf16x8 b0 = *(const bf16x8*)(aT + lr * BSTR + k0);
            bf16x8 b1 = *(const bf16x8*)(aT + (16 + lr) * BSTR + k0);
            acc0 = __builtin_amdgcn_mfma_f32_16x16x32_bf16(a, b0, acc0, 0, 0, 0);
            acc1 = __builtin_amdgcn_mfma_f32_16x16x32_bf16(a, b1, acc1, 0, 0, 0);
        }
        #pragma unroll
        for (int i2 = 0; i2 < 4; ++i2) {
            int o = o0 + lg * 4 + i2;
            float bias = attn_b[o];
            outp[o * TV + lr] = acc0[i2] + bias + xp[o * TV + lr];
            if (lr < 9) {
                int v = 16 + lr;
                outp[o * TV + v] = acc1[i2] + bias + xp[o * TV + v];
            }
        }
    }
}

// ---------------- bn2 stats ----------------
__global__ void bn2_stats_kernel(const float* __restrict__ y,
                                 const float* __restrict__ gamma,
                                 const float* __restrict__ beta,
                                 float* __restrict__ scale,
                                 float* __restrict__ shift) {
    int c = blockIdx.x;
    const float* yp = y + (size_t)c * TV;
    float s = 0.f, s2 = 0.f;
    for (int i = threadIdx.x; i < N_ * TV; i += 256) {
        int n = i / TV, j = i - n * TV;
        float val = yp[(size_t)n * CTV + j];
        s += val; s2 += val * val;
    }
    __shared__ float sh[8];
    #pragma unroll
    for (int off = 32; off; off >>= 1) {
        s  += __shfl_down(s, off, 64);
        s2 += __shfl_down(s2, off, 64);
    }
    int wid = threadIdx.x >> 6, lane = threadIdx.x & 63;
    if (lane == 0) { sh[wid] = s; sh[4 + wid] = s2; }
    __syncthreads();
    if (threadIdx.x == 0) {
        s = sh[0] + sh[1] + sh[2] + sh[3];
        s2 = sh[4] + sh[5] + sh[6] + sh[7];
        float inv = 1.0f / (float)(N_ * TV);
        float mean = s * inv;
        float var = s2 * inv - mean * mean;
        float sc = rsqrtf(var + EPS_) * gamma[c];
        scale[c] = sc;
        shift[c] = beta[c] - mean * sc;
    }
}

__global__ void bn2_apply_kernel(float4* __restrict__ y,
                                 const float* __restrict__ scale,
                                 const float* __restrict__ shift) {
    const int total4 = N_ * CTV / 4;
    for (int i = blockIdx.x * blockDim.x + threadIdx.x; i < total4;
         i += gridDim.x * blockDim.x) {
        int c = (i / (TV / 4)) & 255;
        float4 v = y[i];
        float sc = scale[c], sh = shift[c];
        v.x = fmaxf(fmaf(v.x, sc, sh), 0.f);
        v.y = fmaxf(fmaf(v.y, sc, sh), 0.f);
        v.z = fmaxf(fmaf(v.z, sc, sh), 0.f);
        v.w = fmaxf(fmaf(v.w, sc, sh), 0.f);
        y[i] = v;
    }
}

extern "C" void kernel_launch(void* const* d_in, const int* in_sizes, int n_in,
                              void* d_out, int out_size, void* d_ws, size_t ws_size,
                              hipStream_t stream) {
    const float* x      = (const float*)d_in[0];
    const float* qkv_w  = (const float*)d_in[1];
    const float* qkv_b  = (const float*)d_in[2];
    const float* attn_w = (const float*)d_in[3];
    const float* attn_b = (const float*)d_in[4];
    const float* dbn_g  = (const float*)d_in[5];
    const float* dbn_b  = (const float*)d_in[6];
    const float* bn_g   = (const float*)d_in[7];
    const float* bn_b   = (const float*)d_in[8];
    float* out = (float*)d_out;

    char* ws = (char*)d_ws;
    ushort* Wq      = (ushort*)ws;                       // 448*256*2 = 229376 B
    ushort* Wa      = (ushort*)(ws + 229376);            // 131072 B
    float*  pe      = (float*)(ws + 360448);             // 25600 B
    float*  a_scale = (float*)(ws + 386048);             // 25600 B
    float*  a_shift = (float*)(ws + 411648);             // 25600 B
    float*  bn2_sc  = (float*)(ws + 437248);             // 1024 B
    float*  bn2_sh  = (float*)(ws + 438272);             // 1024 B

    prep_kernel<<<256, 256, 0, stream>>>(qkv_w, attn_w, Wq, Wa, pe);
    dbn_stats_kernel<<<C_ * V_, 256, 0, stream>>>(x, dbn_g, dbn_b, a_scale, a_shift);
    fused_kernel<<<N_ * T_, 512, 0, stream>>>(x, Wq, qkv_b, pe, a_scale, a_shift,
                                              Wa, attn_b, out);
    bn2_stats_kernel<<<C_, 256, 0, stream>>>(out, bn_g, bn_b, bn2_sc, bn2_sh);
    bn2_apply_kernel<<<4096, 256, 0, stream>>>((float4*)out, bn2_sc, bn2_sh);
}

// Round 3
// 608.117 us; speedup vs baseline: 2.4863x; 1.0355x over previous
//
#include <hip/hip_runtime.h>
#include <hip/hip_bf16.h>
#include <math.h>

#define N_   32
#define C_   256
#define T_   128
#define V_   25
#define CTV  (C_ * T_ * V_)   // 819200
#define TV   (T_ * V_)        // 3200
#define EPS_ 1e-5f
#define BSTR 264              // xnT/posT/aT row stride (ushort)
#define QT_STR 328            // qkvT row stride (ushort)
#define VV_STR 40             // qkv_v row stride (ushort)

typedef __attribute__((ext_vector_type(8))) short bf16x8;
typedef __attribute__((ext_vector_type(4))) float f32x4;

__device__ inline ushort f2b(float f) {
    __hip_bfloat16 h = __float2bfloat16(f);
    return *reinterpret_cast<ushort*>(&h);
}
__device__ inline float b2f(ushort u) {
    __hip_bfloat16 h;
    *reinterpret_cast<ushort*>(&h) = u;
    return __bfloat162float(h);
}
__device__ inline float tanh_fast(float x) {
    float xc = fminf(fmaxf(x, -12.f), 12.f);
    float e = __expf(xc + xc);
    return (e - 1.f) * __builtin_amdgcn_rcpf(e + 1.f);
}
#define LD8(p) (*(const bf16x8*)(p))

// ---------------- prep: bf16 weights + PE table ----------------
__global__ void prep_kernel(const float* __restrict__ qkv_w,
                            const float* __restrict__ attn_w,
                            ushort* __restrict__ Wq, ushort* __restrict__ Wa,
                            float* __restrict__ pe) {
    int idx = blockIdx.x * blockDim.x + threadIdx.x;
    int stride = gridDim.x * blockDim.x;
    for (int i = idx; i < 448 * 256; i += stride) Wq[i] = f2b(qkv_w[i]);
    for (int i = idx; i < 256 * 256; i += stride) Wa[i] = f2b(attn_w[i]);
    for (int i = idx; i < C_ * V_; i += stride) {
        int c = i / V_, v = i - c * V_;
        int j2 = c & ~1;
        float ang = (float)v * expf(-logf(10000.0f) * (float)j2 / (float)C_);
        pe[i] = (c & 1) ? cosf(ang) : sinf(ang);
    }
}

// ---------------- data_bn stats, stage 1 (coalesced, LDS-atomic v bins) ----
__global__ void dbn_part_kernel(const float* __restrict__ x,
                                float* __restrict__ ps, float* __restrict__ ps2) {
    __shared__ float binsS[4][32], binsQ[4][32];
    int c = blockIdx.x >> 3, g = blockIdx.x & 7;
    int tid = threadIdx.x, wid = tid >> 6;
    if (tid < 128) { ((float*)binsS)[tid] = 0.f; ((float*)binsQ)[tid] = 0.f; }
    __syncthreads();
    for (int n = g * 4; n < g * 4 + 4; ++n) {
        const float4* p = (const float4*)(x + (size_t)n * CTV + c * TV);
        for (int idx = tid; idx < 800; idx += 256) {
            float4 val = p[idx];
            int v0 = (idx * 4) % 25;
            int v1 = v0 + 1 - ((v0 >= 24) ? 25 : 0);
            int v2 = v1 + 1 - ((v1 >= 24) ? 25 : 0);
            int v3 = v2 + 1 - ((v2 >= 24) ? 25 : 0);
            atomicAdd(&binsS[wid][v0], val.x); atomicAdd(&binsQ[wid][v0], val.x * val.x);
            atomicAdd(&binsS[wid][v1], val.y); atomicAdd(&binsQ[wid][v1], val.y * val.y);
            atomicAdd(&binsS[wid][v2], val.z); atomicAdd(&binsQ[wid][v2], val.z * val.z);
            atomicAdd(&binsS[wid][v3], val.w); atomicAdd(&binsQ[wid][v3], val.w * val.w);
        }
    }
    __syncthreads();
    if (tid < 50) {
        int which = tid / 25, v = tid % 25;
        float s = 0.f;
        #pragma unroll
        for (int w = 0; w < 4; ++w) s += which ? binsQ[w][v] : binsS[w][v];
        (which ? ps2 : ps)[(c * 25 + v) * 8 + g] = s;
    }
}

__global__ void dbn_final_kernel(const float* __restrict__ ps,
                                 const float* __restrict__ ps2,
                                 const float* __restrict__ gamma,
                                 const float* __restrict__ beta,
                                 float* __restrict__ a_scale,
                                 float* __restrict__ a_shift) {
    int i = blockIdx.x * 512 + threadIdx.x;
    if (i >= 6400) return;
    float s = 0.f, q = 0.f;
    #pragma unroll
    for (int g = 0; g < 8; ++g) { s += ps[i * 8 + g]; q += ps2[i * 8 + g]; }
    float inv = 1.f / 4096.f;
    float mean = s * inv, var = q * inv - mean * mean;
    float sc = rsqrtf(var + EPS_) * gamma[i];
    a_scale[i] = sc;
    a_shift[i] = beta[i] - mean * sc;
}

// ---------------- fused per-token kernel ----------------
// qkvT cols: 0..63 q | 64..127 k | 128..191 g | 192..255 pq | 256..319 pk
__global__ __launch_bounds__(512, 4) void fused_kernel(
        const float* __restrict__ x,
        const ushort* __restrict__ Wq, const float* __restrict__ qkv_b,
        const float* __restrict__ pe,
        const float* __restrict__ a_scale, const float* __restrict__ a_shift,
        const ushort* __restrict__ Wa, const float* __restrict__ attn_b,
        float* __restrict__ out) {
    __shared__ __align__(16) char smem[77568];
    ushort* xnT  = (ushort*)smem;                 // [32][264] -> later aT
    ushort* posT = (ushort*)(smem + 16896);       // [32][264] -> later pbuf[8][32][32]
    ushort* qkvT = (ushort*)(smem + 33792);       // [32][328]
    ushort* qkvV = (ushort*)(smem + 54784);       // [256][40]
    float*  qmu  = (float*)(smem + 75264);        // 64
    float*  u1   = (float*)(smem + 75520);        // [8][32]
    float*  u2   = (float*)(smem + 76544);        // [8][32]
    ushort* aT   = xnT;
    ushort* pbuf = posT;

    int blk = blockIdx.x;
    int n = blk >> 7, t = blk & 127;
    int tid = threadIdx.x;
    int wave = tid >> 6, lane = tid & 63;
    int lr = lane & 15, lg = lane >> 4;
    const float* xp = x + (size_t)n * CTV + t * V_;
    const bf16x8 zero8 = {0, 0, 0, 0, 0, 0, 0, 0};
    const f32x4 zacc = {0.f, 0.f, 0.f, 0.f};

    // ---- stage: xnT[v][c], posT[v][c] ----
    for (int i = tid; i < 6400; i += 512) {
        int c = i / 25, v = i - c * 25;
        float xv = xp[c * TV + v];
        xnT[v * BSTR + c]  = f2b(fmaf(xv, a_scale[i], a_shift[i]));
        posT[v * BSTR + c] = f2b(xv + pe[i]);
    }
    for (int i = tid; i < 7 * 256; i += 512) {
        int v = 25 + (i >> 8), c = i & 255;
        xnT[v * BSTR + c] = 0; posT[v * BSTR + c] = 0;
    }
    __syncthreads();

    // ---- GEMM1: 36 tiles of W(576x256) x B(256x25) ----
    for (int mt = wave; mt < 36; mt += 8) {
        const ushort* Bsrc = (mt < 28) ? xnT : posT;
        int r0 = mt * 16;
        int wr0 = (mt < 28) ? r0 : (r0 - 448);
        const ushort* Arow = Wq + (wr0 + lr) * 256;
        f32x4 acc0 = zacc, acc1 = zacc;
        #pragma unroll
        for (int kk = 0; kk < 8; ++kk) {
            int k0 = kk * 32 + lg * 8;
            bf16x8 a  = LD8(Arow + k0);
            bf16x8 b0 = LD8(Bsrc + lr * BSTR + k0);
            bf16x8 b1 = LD8(Bsrc + (16 + lr) * BSTR + k0);
            acc0 = __builtin_amdgcn_mfma_f32_16x16x32_bf16(a, b0, acc0, 0, 0, 0);
            acc1 = __builtin_amdgcn_mfma_f32_16x16x32_bf16(a, b1, acc1, 0, 0, 0);
        }
        float scale = (mt < 4 || (mt >= 28 && mt < 32)) ? 0.35355339059327373f : 1.0f;
        if (mt < 12 || mt >= 28) {   // q,k,g,pq,pk -> transposed store
            #pragma unroll
            for (int i2 = 0; i2 < 4; ++i2) {
                int rr = r0 + lg * 4 + i2;
                int col = (rr < 192) ? rr : (rr - 256);
                float bias = qkv_b[wr0 + lg * 4 + i2];
                qkvT[lr * QT_STR + col] = f2b((acc0[i2] + bias) * scale);
                qkvT[(16 + lr) * QT_STR + col] =
                    (lr < 9) ? f2b((acc1[i2] + bias) * scale) : (ushort)0;
            }
        } else {                     // v rows -> row-major store [e][w]
            #pragma unroll
            for (int i2 = 0; i2 < 4; ++i2) {
                int e = r0 - 192 + lg * 4 + i2;
                float bias = qkv_b[wr0 + lg * 4 + i2];
                qkvV[e * VV_STR + lr] = f2b(acc0[i2] + bias);
                qkvV[e * VV_STR + 16 + lr] = (lr < 9) ? f2b(acc1[i2] + bias) : (ushort)0;
            }
        }
    }
    __syncthreads();

    // ---- q mean over joints (q cols 0..63) ----
    if (tid < 64) {
        float s = 0.f;
        #pragma unroll
        for (int v = 0; v < 25; ++v) s += b2f(qkvT[v * QT_STR + tid]);
        qmu[tid] = s * (1.0f / 25.0f);
    }
    __syncthreads();

    // ---- u1 = mu^T k, u2 = mu^T g (VALU, tiny) + weights MFMAs ----
    if (tid < 200) {
        int h = tid / 25, w = tid - h * 25;
        float s1 = 0.f, s2v = 0.f;
        #pragma unroll
        for (int d = 0; d < 8; ++d) {
            float m = qmu[h * 8 + d];
            s1  = fmaf(m, b2f(qkvT[w * QT_STR + 64 + h * 8 + d]), s1);
            s2v = fmaf(m, b2f(qkvT[w * QT_STR + 128 + h * 8 + d]), s2v);
        }
        u1[h * 32 + w] = s1;
        u2[h * 32 + w] = s2v;
    }

    int h = wave;  // wave == head
    // P1 = [q;pq]^T [k;pk] (K=16), P2 = pq^T pk (K=8)
    bf16x8 aP1[2], aP2[2], bP1[2], bP2[2];
    #pragma unroll
    for (int mi = 0; mi < 2; ++mi) {
        const ushort* row = qkvT + (mi * 16 + lr) * QT_STR;
        aP1[mi] = (lg == 0) ? LD8(row + h * 8)
                : (lg == 1) ? LD8(row + 192 + h * 8) : zero8;
        aP2[mi] = (lg == 0) ? LD8(row + 192 + h * 8) : zero8;
        bP1[mi] = (lg == 0) ? LD8(row + 64 + h * 8)
                : (lg == 1) ? LD8(row + 256 + h * 8) : zero8;
        bP2[mi] = (lg == 0) ? LD8(row + 256 + h * 8) : zero8;
    }
    f32x4 p1[2][2], p2[2][2];
    #pragma unroll
    for (int mi = 0; mi < 2; ++mi)
        #pragma unroll
        for (int ni = 0; ni < 2; ++ni) {
            p1[mi][ni] = __builtin_amdgcn_mfma_f32_16x16x32_bf16(aP1[mi], bP1[ni], zacc, 0, 0, 0);
            p2[mi][ni] = __builtin_amdgcn_mfma_f32_16x16x32_bf16(aP2[mi], bP2[ni], zacc, 0, 0, 0);
        }
    __syncthreads();   // u1/u2 visible; posT no longer needed

    // ---- weights = tanh(P1-u1) + tanh(P2+u2) -> pbuf[h][v][w] bf16 ----
    #pragma unroll
    for (int mi = 0; mi < 2; ++mi)
        #pragma unroll
        for (int ni = 0; ni < 2; ++ni)
            #pragma unroll
            for (int i2 = 0; i2 < 4; ++i2) {
                int v = mi * 16 + lg * 4 + i2;
                int w = ni * 16 + lr;
                int wc = (w < 25) ? w : 0;
                float uu1 = u1[h * 32 + wc], uu2 = u2[h * 32 + wc];
                float tw = tanh_fast(p1[mi][ni][i2] - uu1) + tanh_fast(p2[mi][ni][i2] + uu2);
                pbuf[h * 1024 + v * 32 + w] = (w < 25) ? f2b(tw) : (ushort)0;
            }
    __syncthreads();

    // ---- attn = V x weights^T -> aT[v][e] ----
    {
        bf16x8 av[2], bw[2];
        #pragma unroll
        for (int mi = 0; mi < 2; ++mi)
            av[mi] = LD8(qkvV + (h * 32 + mi * 16 + lr) * VV_STR + lg * 8);
        #pragma unroll
        for (int ni = 0; ni < 2; ++ni)
            bw[ni] = LD8(pbuf + h * 1024 + (ni * 16 + lr) * 32 + lg * 8);
        f32x4 at_[2][2];
        #pragma unroll
        for (int mi = 0; mi < 2; ++mi)
            #pragma unroll
            for (int ni = 0; ni < 2; ++ni)
                at_[mi][ni] = __builtin_amdgcn_mfma_f32_16x16x32_bf16(av[mi], bw[ni], zacc, 0, 0, 0);
        __syncthreads();   // xnT (aT region) free
        #pragma unroll
        for (int mi = 0; mi < 2; ++mi)
            #pragma unroll
            for (int ni = 0; ni < 2; ++ni)
                #pragma unroll
                for (int i2 = 0; i2 < 4; ++i2) {
                    int ge = h * 32 + mi * 16 + lg * 4 + i2;
                    int v = ni * 16 + lr;
                    aT[v * BSTR + ge] = (v < 25) ? f2b(at_[mi][ni][i2]) : (ushort)0;
                }
    }
    __syncthreads();

    // ---- GEMM2: out = attn_w(256x256) x aT^T + bias + skip ----
    float* outp = out + (size_t)n * CTV + t * V_;
    for (int mt = wave; mt < 16; mt += 8) {
        int o0 = mt * 16;
        const ushort* Arow = Wa + (o0 + lr) * 256;
        f32x4 acc0 = zacc, acc1 = zacc;
        #pragma unroll
        for (int kk = 0; kk < 8; ++kk) {
            int k0 = kk * 32 + lg * 8;
            bf16x8 a  = LD8(Arow + k0);
            bf16x8 b0 = LD8(aT + lr * BSTR + k0);
            bf16x8 b1 = LD8(aT + (16 + lr) * BSTR + k0);
            acc0 = __builtin_amdgcn_mfma_f32_16x16x32_bf16(a, b0, acc0, 0, 0, 0);
            acc1 = __builtin_amdgcn_mfma_f32_16x16x32_bf16(a, b1, acc1, 0, 0, 0);
        }
        #pragma unroll
        for (int i2 = 0; i2 < 4; ++i2) {
            int o = o0 + lg * 4 + i2;
            float bias = attn_b[o];
            outp[o * TV + lr] = acc0[i2] + bias + xp[o * TV + lr];
            if (lr < 9) {
                int v = 16 + lr;
                outp[o * TV + v] = acc1[i2] + bias + xp[o * TV + v];
            }
        }
    }
}

// ---------------- bn2 stats, two stage ----------------
__global__ void bn2_part_kernel(const float* __restrict__ y,
                                float* __restrict__ bp_s, float* __restrict__ bp_q) {
    int c = blockIdx.x >> 3, g = blockIdx.x & 7;
    int tid = threadIdx.x, wid = tid >> 6, lane = tid & 63;
    float s = 0.f, s2 = 0.f;
    for (int n = g * 4; n < g * 4 + 4; ++n) {
        const float4* p = (const float4*)(y + (size_t)n * CTV + c * TV);
        for (int idx = tid; idx < 800; idx += 256) {
            float4 v = p[idx];
            s  += v.x + v.y + v.z + v.w;
            s2 += v.x * v.x + v.y * v.y + v.z * v.z + v.w * v.w;
        }
    }
    __shared__ float sh[8];
    #pragma unroll
    for (int off = 32; off; off >>= 1) {
        s  += __shfl_down(s, off, 64);
        s2 += __shfl_down(s2, off, 64);
    }
    if (lane == 0) { sh[wid] = s; sh[4 + wid] = s2; }
    __syncthreads();
    if (tid == 0) {
        bp_s[c * 8 + g] = sh[0] + sh[1] + sh[2] + sh[3];
        bp_q[c * 8 + g] = sh[4] + sh[5] + sh[6] + sh[7];
    }
}

__global__ void bn2_final_kernel(const float* __restrict__ bp_s,
                                 const float* __restrict__ bp_q,
                                 const float* __restrict__ gamma,
                                 const float* __restrict__ beta,
                                 float* __restrict__ scale,
                                 float* __restrict__ shift) {
    int c = threadIdx.x;
    float s = 0.f, q = 0.f;
    #pragma unroll
    for (int g = 0; g < 8; ++g) { s += bp_s[c * 8 + g]; q += bp_q[c * 8 + g]; }
    float inv = 1.0f / (float)(N_ * TV);
    float mean = s * inv, var = q * inv - mean * mean;
    float sc = rsqrtf(var + EPS_) * gamma[c];
    scale[c] = sc;
    shift[c] = beta[c] - mean * sc;
}

__global__ void bn2_apply_kernel(float4* __restrict__ y,
                                 const float* __restrict__ scale,
                                 const float* __restrict__ shift) {
    const int total4 = N_ * CTV / 4;
    for (int i = blockIdx.x * blockDim.x + threadIdx.x; i < total4;
         i += gridDim.x * blockDim.x) {
        int c = (i / (TV / 4)) & 255;
        float4 v = y[i];
        float sc = scale[c], sh = shift[c];
        v.x = fmaxf(fmaf(v.x, sc, sh), 0.f);
        v.y = fmaxf(fmaf(v.y, sc, sh), 0.f);
        v.z = fmaxf(fmaf(v.z, sc, sh), 0.f);
        v.w = fmaxf(fmaf(v.w, sc, sh), 0.f);
        y[i] = v;
    }
}

extern "C" void kernel_launch(void* const* d_in, const int* in_sizes, int n_in,
                              void* d_out, int out_size, void* d_ws, size_t ws_size,
                              hipStream_t stream) {
    const float* x      = (const float*)d_in[0];
    const float* qkv_w  = (const float*)d_in[1];
    const float* qkv_b  = (const float*)d_in[2];
    const float* attn_w = (const float*)d_in[3];
    const float* attn_b = (const float*)d_in[4];
    const float* dbn_g  = (const float*)d_in[5];
    const float* dbn_b  = (const float*)d_in[6];
    const float* bn_g   = (const float*)d_in[7];
    const float* bn_b   = (const float*)d_in[8];
    float* out = (float*)d_out;

    char* ws = (char*)d_ws;
    ushort* Wq      = (ushort*)ws;                 // 229376 B
    ushort* Wa      = (ushort*)(ws + 229376);      // 131072 B
    float*  pe      = (float*)(ws + 360448);       // 25600 B
    float*  a_scale = (float*)(ws + 386048);       // 25600 B
    float*  a_shift = (float*)(ws + 411648);       // 25600 B
    float*  bn2_sc  = (float*)(ws + 437248);       // 1024 B
    float*  bn2_sh  = (float*)(ws + 438272);       // 1024 B
    float*  dbn_ps  = (float*)(ws + 439296);       // 204800 B
    float*  dbn_ps2 = (float*)(ws + 644096);       // 204800 B
    float*  bp_s    = (float*)(ws + 848896);       // 8192 B
    float*  bp_q    = (float*)(ws + 857088);       // 8192 B

    prep_kernel<<<256, 256, 0, stream>>>(qkv_w, attn_w, Wq, Wa, pe);
    dbn_part_kernel<<<2048, 256, 0, stream>>>(x, dbn_ps, dbn_ps2);
    dbn_final_kernel<<<13, 512, 0, stream>>>(dbn_ps, dbn_ps2, dbn_g, dbn_b,
                                             a_scale, a_shift);
    fused_kernel<<<N_ * T_, 512, 0, stream>>>(x, Wq, qkv_b, pe, a_scale, a_shift,
                                              Wa, attn_b, out);
    bn2_part_kernel<<<2048, 256, 0, stream>>>(out, bp_s, bp_q);
    bn2_final_kernel<<<1, 256, 0, stream>>>(bp_s, bp_q, bn_g, bn_b, bn2_sc, bn2_sh);
    bn2_apply_kernel<<<4096, 256, 0, stream>>>((float4*)out, bn2_sc, bn2_sh);
}